// Round 2
// baseline (873.784 us; speedup 1.0000x reference)
//
#include <hip/hip_runtime.h>
#include <math.h>

#define HDIM 4096
#define NEXP 64
#define NTOK 16384
#define MBLK 32      // tokens per block
#define TT   16      // token tile (acc rows per lane)  [R6: 8 -> 16, halves gate traffic]
#define KC   256     // k-chunk: lane l owns k = 4l..4l+3
#define NCHUNK (HDIM / KC)       // 16
#define NTILE  (MBLK / TT)       // 2
#define NITER  (NTILE * NCHUNK)  // 32
#define CSTRIDE 68

typedef float v4f __attribute__((ext_vector_type(4)));

// DPP-add helper: x + dpp_select(x); masked-out rows contribute 0.
template <int CTRL, int RMASK>
__device__ __forceinline__ float dpp_add(float x) {
    int xi = __builtin_bit_cast(int, x);
    int yi = __builtin_amdgcn_update_dpp(0, xi, CTRL, RMASK, 0xF, true);
    return x + __builtin_bit_cast(float, yi);
}

// Fused router. 512 blocks x 512 threads.
// R6 theory: gate traffic = (NTOK/TT) x 1MB. TT=8 -> 2.1 GB of gate re-reads
// served at ~8 TB/s (L3; A-stream evicts gate from per-XCD L2 every 16 iters,
// nt bit on A was neutral). TT=16 halves gate traffic and doubles compute per
// exposed gate-load latency; g register double-buffer hides the rest.
// VGPR: acc 128 + g_cur 32 + g_next 32 + pref 8 + misc -> needs the 256 cap,
// hence __launch_bounds__(512,1) (2nd arg = min blocks/CU on this toolchain;
// (512,2) would cap at 128 VGPRs and spill the accumulator).
__global__ __launch_bounds__(512, 1) void router_main(
    const float* __restrict__ hidden,
    const float* __restrict__ gate,
    float* __restrict__ out_rw,
    float* __restrict__ out_sel,
    float* __restrict__ psum_g,
    float* __restrict__ cnt_g,
    float* __restrict__ zsum_g)
{
    __shared__ float A_lds[2][TT * KC];       // 2 x 16 KB
    __shared__ float C_lds[MBLK * CSTRIDE];
    __shared__ float rden[MBLK];
    __shared__ unsigned hist[NEXP];

    const int t = threadIdx.x;
    const int lane = t & 63;
    const int wave = __builtin_amdgcn_readfirstlane(t >> 6);
    const int m0 = blockIdx.x * MBLK;

    const v4f* __restrict__ A4 = (const v4f*)hidden;         // row = 1024 float4
    const float4* __restrict__ G4 = (const float4*)gate;

    // A fragment for iter j, sub-row r (each wave stages 2 rows of the 16-row tile):
    // token row = m0 + (j>>4)*TT + wave*2 + r, float4 col (j&15)*64 + lane.
    // Non-temporal: A has zero reuse.
    auto a_load = [&](int j, int r) -> v4f {
        return __builtin_nontemporal_load(
            &A4[(size_t)(m0 + (j >> 4) * TT + wave * 2 + r) * (HDIM / 4) + (j & 15) * (KC / 4) + lane]);
    };

    float acc[TT][8];
#pragma unroll
    for (int tt = 0; tt < TT; ++tt)
#pragma unroll
        for (int e = 0; e < 8; ++e) acc[tt][e] = 0.f;

    // prologue: stage iter 0, prefetch iter 1, preload gate chunk 0
    v4f pref[2];
    pref[0] = a_load(0, 0);
    pref[1] = a_load(0, 1);
    *(v4f*)&A_lds[0][(wave * 2 + 0) * KC + lane * 4] = pref[0];
    *(v4f*)&A_lds[0][(wave * 2 + 1) * KC + lane * 4] = pref[1];
    pref[0] = a_load(1, 0);
    pref[1] = a_load(1, 1);

    float4 g_cur[8], g_next[8];
#pragma unroll
    for (int e = 0; e < 8; ++e)
        g_cur[e] = G4[(size_t)(wave * 8 + e) * (HDIM / 4) + lane];   // chunk 0
    __syncthreads();

#pragma unroll 2
    for (int it = 0; it < NITER; ++it) {
        const int cur = it & 1;
        // prefetch NEXT chunk's gate fragment (used next iteration; latency
        // hidden under this iteration's 512 FMAs)
        if (it + 1 < NITER) {
            const int cn = (it + 1) & 15;
#pragma unroll
            for (int e = 0; e < 8; ++e)
                g_next[e] = G4[(size_t)(wave * 8 + e) * (HDIM / 4) + cn * (KC / 4) + lane];
        }
        // stage next chunk's A tile into the other buffer
        if (it + 1 < NITER) {
            *(v4f*)&A_lds[cur ^ 1][(wave * 2 + 0) * KC + lane * 4] = pref[0];
            *(v4f*)&A_lds[cur ^ 1][(wave * 2 + 1) * KC + lane * 4] = pref[1];
        }
        // prefetch A for iter+2
        if (it + 2 < NITER) {
            pref[0] = a_load(it + 2, 0);
            pref[1] = a_load(it + 2, 1);
        }
        // compute: per token 1 ds_read_b128 -> 32 FMAs (16 tokens x 8 experts x 4k)
#pragma unroll
        for (int tt = 0; tt < TT; ++tt) {
            v4f a = *(const v4f*)&A_lds[cur][tt * KC + lane * 4];
#pragma unroll
            for (int e = 0; e < 8; ++e) {
                acc[tt][e] = fmaf(a.x, g_cur[e].x, acc[tt][e]);
                acc[tt][e] = fmaf(a.y, g_cur[e].y, acc[tt][e]);
                acc[tt][e] = fmaf(a.z, g_cur[e].z, acc[tt][e]);
                acc[tt][e] = fmaf(a.w, g_cur[e].w, acc[tt][e]);
            }
        }
        // end of tile: cross-lane K-reduction (6 DPP adds -> lanes 48..63), flush
        if ((it & 15) == 15) {
            const int tile = it >> 4;
#pragma unroll
            for (int tt = 0; tt < TT; ++tt)
#pragma unroll
                for (int e = 0; e < 8; ++e) {
                    float x = acc[tt][e];
                    x = dpp_add<0xB1,  0xF>(x);   // quad_perm xor1
                    x = dpp_add<0x4E,  0xF>(x);   // quad_perm xor2
                    x = dpp_add<0x141, 0xF>(x);   // row_half_mirror
                    x = dpp_add<0x140, 0xF>(x);   // row_mirror
                    x = dpp_add<0x142, 0xA>(x);   // bcast15
                    x = dpp_add<0x143, 0xC>(x);   // bcast31
                    acc[tt][e] = x;
                }
            if (lane == 48) {
#pragma unroll
                for (int tt = 0; tt < TT; ++tt) {
                    *(float4*)&C_lds[(tile * TT + tt) * CSTRIDE + wave * 8 + 0] =
                        make_float4(acc[tt][0], acc[tt][1], acc[tt][2], acc[tt][3]);
                    *(float4*)&C_lds[(tile * TT + tt) * CSTRIDE + wave * 8 + 4] =
                        make_float4(acc[tt][4], acc[tt][5], acc[tt][6], acc[tt][7]);
                }
            }
#pragma unroll
            for (int tt = 0; tt < TT; ++tt)
#pragma unroll
                for (int e = 0; e < 8; ++e) acc[tt][e] = 0.f;
        }
        __syncthreads();
        // rotate gate double-buffer (register renaming under unroll-2)
        if (it + 1 < NITER) {
#pragma unroll
            for (int e = 0; e < 8; ++e) g_cur[e] = g_next[e];
        }
    }

    if (t < NEXP) hist[t] = 0u;
    __syncthreads();

    if (wave != 0) return;   // epilogue on wave 0 (lanes 0..31 = tokens)

    float z = 0.f;
    if (lane < MBLK) {
        // top-2 (strict >, ascending e => ties pick lower index, matches jax)
        float v1 = -INFINITY, v2 = -INFINITY;
        int i1 = 0, i2 = 0;
        for (int e = 0; e < NEXP; ++e) {
            float v = C_lds[lane * CSTRIDE + e];
            if (v > v1)      { v2 = v1; i2 = i1; v1 = v; i1 = e; }
            else if (v > v2) { v2 = v;  i2 = e; }
        }
        atomicAdd(&hist[i1], 1u);
        atomicAdd(&hist[i2], 1u);

        float d = 0.f;
        for (int e = 0; e < NEXP; ++e) {
            float ev = expf(C_lds[lane * CSTRIDE + e] - v1);
            C_lds[lane * CSTRIDE + e] = ev;
            d += ev;
        }
        rden[lane] = 1.0f / d;
        float lse = v1 + logf(d);
        z = lse * lse;

        float e2 = expf(v2 - v1);
        float w2 = e2 / (1.f + e2);
        float w1 = 1.f - w2;
        int tok = m0 + lane;
        out_rw[2 * tok + 0] = w1;
        out_rw[2 * tok + 1] = w2;
        out_sel[2 * tok + 0] = (float)i1;
        out_sel[2 * tok + 1] = (float)i2;
    }

#pragma unroll
    for (int off = 32; off > 0; off >>= 1) z += __shfl_down(z, off);
    if (lane == 0) atomicAdd(zsum_g, z);

    // per-expert prob sums over this block's 32 tokens (lane = expert)
    float ps = 0.f;
    for (int m = 0; m < MBLK; ++m)
        ps += C_lds[m * CSTRIDE + lane] * rden[m];
    atomicAdd(&psum_g[lane], ps);
    atomicAdd(&cnt_g[lane], (float)hist[lane]);
}

__global__ void router_final(const float* __restrict__ ws, float* __restrict__ out_loss)
{
    int e = threadIdx.x;  // 64 threads
    const float inv = 1.0f / (float)NTOK;
    float p = (ws[64 + e] * inv) * (ws[e] * inv);
#pragma unroll
    for (int off = 32; off > 0; off >>= 1) p += __shfl_down(p, off);
    if (e == 0)
        out_loss[0] = 0.01f * (64.f * p) + 0.001f * (ws[128] * inv);
}

extern "C" void kernel_launch(void* const* d_in, const int* in_sizes, int n_in,
                              void* d_out, int out_size, void* d_ws, size_t ws_size,
                              hipStream_t stream) {
    const float* hidden = (const float*)d_in[0];   // [4,4096,4096] fp32
    const float* gate   = (const float*)d_in[1];   // [64,4096] fp32
    float* out = (float*)d_out;                    // 65537 floats
    float* ws  = (float*)d_ws;                     // psum[64] | cnt[64] | zsum[1]

    hipMemsetAsync(d_ws, 0, 129 * sizeof(float), stream);
    router_main<<<dim3(NTOK / MBLK), dim3(512), 0, stream>>>(
        hidden, gate,
        out,                 // routing weights
        out + NTOK * 2,      // selected experts (as floats)
        ws, ws + 64, ws + 128);
    router_final<<<dim3(1), dim3(64), 0, stream>>>(ws, out + NTOK * 4);
}

// Round 3
// 456.553 us; speedup vs baseline: 1.9139x; 1.9139x over previous
//
#include <hip/hip_runtime.h>
#include <math.h>

#define HDIM 4096
#define NEXP 64
#define NTOK 16384
#define MBLK 32            // tokens per block (all amortize one gate pass)
#define KC   64            // k per chunk
#define NCHUNK (HDIM / KC) // 64
#define ASTR 68            // padded floats per token row in A_lds (64 + 4) -> conflict-free
#define CSTRIDE 68

typedef float v4f __attribute__((ext_vector_type(4)));

// DPP-add helper: x + dpp_select(x).
template <int CTRL, int RMASK>
__device__ __forceinline__ float dpp_add(float x) {
    int xi = __builtin_bit_cast(int, x);
    int yi = __builtin_amdgcn_update_dpp(0, xi, CTRL, RMASK, 0xF, true);
    return x + __builtin_bit_cast(float, yi);
}

// Fused router. 512 blocks x 512 threads.
// R7 structure: lane = e_sub*16 + k_sub. Wave w owns experts {8w+e_sub} (eg0)
// and {8w+4+e_sub} (eg1); lane's k-slice = 4 floats per 64-k chunk.
// acc[MBLK][2] = 64 VGPRs: whole 32-token block amortizes each gate fragment
// -> gate traffic 2 GB (R1) -> 512 MB. Gate reg-double-buffered (loaded one
// chunk ahead, consumed under 512 FMA-cycles). A per-chunk in LDS, padded
// rows (68 floats) -> conflict-free ds_read_b128/ds_write_b128.
// K-reduce: 4 DPP butterfly steps over k_sub, ONCE after the chunk loop.
// VGPR ~105: fits the (512,2)=128-cap proven safe in R1 (no spill).
__global__ __launch_bounds__(512, 2) void router_main(
    const float* __restrict__ hidden,
    const float* __restrict__ gate,
    float* __restrict__ out_rw,
    float* __restrict__ out_sel,
    float* __restrict__ psum_g,
    float* __restrict__ cnt_g,
    float* __restrict__ zsum_g)
{
    __shared__ float A_lds[2][MBLK * ASTR];   // 2 x 8.5 KB
    __shared__ float C_lds[MBLK * CSTRIDE];
    __shared__ float rden[MBLK];
    __shared__ unsigned hist[NEXP];

    const int t = threadIdx.x;
    const int lane = t & 63;
    const int wave = __builtin_amdgcn_readfirstlane(t >> 6);
    const int m0 = blockIdx.x * MBLK;
    const int ksub = lane & 15;   // k-slice owner: k = c*64 + ksub*4 .. +3
    const int esub = lane >> 4;   // expert sub-index 0..3

    const v4f* __restrict__ A4 = (const v4f*)hidden;   // token row = 1024 f4
    const v4f* __restrict__ G4 = (const v4f*)gate;     // expert row = 1024 f4

    // staging assignment: thread t stages token st = t>>4, f4-col sc = t&15
    const int st = t >> 4;
    const int sc = t & 15;
    const size_t arow = (size_t)(m0 + st) * (HDIM / 4);

    // gate rows for this lane's two expert groups
    const size_t grow0 = (size_t)(8 * wave + esub) * (HDIM / 4);
    const size_t grow1 = (size_t)(8 * wave + 4 + esub) * (HDIM / 4);

    float acc[MBLK][2];
#pragma unroll
    for (int tt = 0; tt < MBLK; ++tt) { acc[tt][0] = 0.f; acc[tt][1] = 0.f; }

    // prologue: stage chunk 0, prefetch A chunk 1, preload gate chunk 0
    v4f apref = __builtin_nontemporal_load(&A4[arow + sc]);
    *(v4f*)&A_lds[0][st * ASTR + sc * 4] = apref;
    apref = __builtin_nontemporal_load(&A4[arow + 16 + sc]);
    v4f gc0 = G4[grow0 + ksub];
    v4f gc1 = G4[grow1 + ksub];
    __syncthreads();

    for (int it = 0; it < NCHUNK; ++it) {
        const int cur = it & 1;
        // prefetch next chunk's gate fragments (consumed next iteration)
        const int cn = (it + 1 < NCHUNK) ? (it + 1) : (NCHUNK - 1);
        v4f gn0 = G4[grow0 + cn * 16 + ksub];
        v4f gn1 = G4[grow1 + cn * 16 + ksub];
        // stage next chunk's A tile into the other buffer
        if (it + 1 < NCHUNK)
            *(v4f*)&A_lds[cur ^ 1][st * ASTR + sc * 4] = apref;
        // prefetch A for chunk it+2
        const int ca = (it + 2 < NCHUNK) ? (it + 2) : (NCHUNK - 1);
        apref = __builtin_nontemporal_load(&A4[arow + ca * 16 + sc]);
        // compute: 32 tokens x (1 ds_read_b128 -> 8 FMAs)
        const float* Ab = &A_lds[cur][ksub * 4];
#pragma unroll
        for (int tt = 0; tt < MBLK; ++tt) {
            v4f a = *(const v4f*)&Ab[tt * ASTR];
            acc[tt][0] = fmaf(a.x, gc0.x, acc[tt][0]);
            acc[tt][0] = fmaf(a.y, gc0.y, acc[tt][0]);
            acc[tt][0] = fmaf(a.z, gc0.z, acc[tt][0]);
            acc[tt][0] = fmaf(a.w, gc0.w, acc[tt][0]);
            acc[tt][1] = fmaf(a.x, gc1.x, acc[tt][1]);
            acc[tt][1] = fmaf(a.y, gc1.y, acc[tt][1]);
            acc[tt][1] = fmaf(a.z, gc1.z, acc[tt][1]);
            acc[tt][1] = fmaf(a.w, gc1.w, acc[tt][1]);
        }
        __syncthreads();
        gc0 = gn0;
        gc1 = gn1;
    }

    // k-reduction: butterfly over k_sub (lane bits 0..3): xor1, xor2, xor4, xor8
#pragma unroll
    for (int tt = 0; tt < MBLK; ++tt)
#pragma unroll
        for (int eg = 0; eg < 2; ++eg) {
            float x = acc[tt][eg];
            x = dpp_add<0xB1,  0xF>(x);   // quad_perm xor1
            x = dpp_add<0x4E,  0xF>(x);   // quad_perm xor2
            x = dpp_add<0x141, 0xF>(x);   // row_half_mirror (xor4 after quad-sums)
            x = dpp_add<0x140, 0xF>(x);   // row_mirror (xor8 after 8-sums)
            acc[tt][eg] = x;
        }
    if (ksub == 0) {
#pragma unroll
        for (int tt = 0; tt < MBLK; ++tt) {
            C_lds[tt * CSTRIDE + wave * 8 + esub]     = acc[tt][0];
            C_lds[tt * CSTRIDE + wave * 8 + 4 + esub] = acc[tt][1];
        }
    }

    if (t < NEXP) hist[t] = 0u;
    __syncthreads();

    if (wave != 0) return;   // epilogue on wave 0 (lanes 0..31 = tokens)

    float z = 0.f;
    if (lane < MBLK) {
        // top-2 (strict >, ascending e => ties pick lower index, matches jax)
        float v1 = -INFINITY, v2 = -INFINITY;
        int i1 = 0, i2 = 0;
        for (int e = 0; e < NEXP; ++e) {
            float v = C_lds[lane * CSTRIDE + e];
            if (v > v1)      { v2 = v1; i2 = i1; v1 = v; i1 = e; }
            else if (v > v2) { v2 = v;  i2 = e; }
        }
        atomicAdd(&hist[i1], 1u);
        atomicAdd(&hist[i2], 1u);

        float d = 0.f;
        for (int e = 0; e < NEXP; ++e) {
            float ev = expf(C_lds[lane * CSTRIDE + e] - v1);
            C_lds[lane * CSTRIDE + e] = ev;
            d += ev;
        }
        rden[lane] = 1.0f / d;
        float lse = v1 + logf(d);
        z = lse * lse;

        float e2 = expf(v2 - v1);
        float w2 = e2 / (1.f + e2);
        float w1 = 1.f - w2;
        int tok = m0 + lane;
        out_rw[2 * tok + 0] = w1;
        out_rw[2 * tok + 1] = w2;
        out_sel[2 * tok + 0] = (float)i1;
        out_sel[2 * tok + 1] = (float)i2;
    }

#pragma unroll
    for (int off = 32; off > 0; off >>= 1) z += __shfl_down(z, off);
    if (lane == 0) atomicAdd(zsum_g, z);

    // per-expert prob sums over this block's 32 tokens (lane = expert)
    float ps = 0.f;
    for (int m = 0; m < MBLK; ++m)
        ps += C_lds[m * CSTRIDE + lane] * rden[m];
    atomicAdd(&psum_g[lane], ps);
    atomicAdd(&cnt_g[lane], (float)hist[lane]);
}

__global__ void router_final(const float* __restrict__ ws, float* __restrict__ out_loss)
{
    int e = threadIdx.x;  // 64 threads
    const float inv = 1.0f / (float)NTOK;
    float p = (ws[64 + e] * inv) * (ws[e] * inv);
#pragma unroll
    for (int off = 32; off > 0; off >>= 1) p += __shfl_down(p, off);
    if (e == 0)
        out_loss[0] = 0.01f * (64.f * p) + 0.001f * (ws[128] * inv);
}

extern "C" void kernel_launch(void* const* d_in, const int* in_sizes, int n_in,
                              void* d_out, int out_size, void* d_ws, size_t ws_size,
                              hipStream_t stream) {
    const float* hidden = (const float*)d_in[0];   // [4,4096,4096] fp32
    const float* gate   = (const float*)d_in[1];   // [64,4096] fp32
    float* out = (float*)d_out;                    // 65537 floats
    float* ws  = (float*)d_ws;                     // psum[64] | cnt[64] | zsum[1]

    hipMemsetAsync(d_ws, 0, 129 * sizeof(float), stream);
    router_main<<<dim3(NTOK / MBLK), dim3(512), 0, stream>>>(
        hidden, gate,
        out,                 // routing weights
        out + NTOK * 2,      // selected experts (as floats)
        ws, ws + 64, ws + 128);
    router_final<<<dim3(1), dim3(64), 0, stream>>>(ws, out + NTOK * 4);
}